// Round 5
// baseline (1445.281 us; speedup 1.0000x reference)
//
#include <hip/hip_runtime.h>
#include <cstdint>
#include <math.h>

#define BATCH    65536
#define HIS_LEN  5
#define KIND_LEN 10

// ---- ws layout (fp32 element offsets) ----
#define OFF_WC1 0        // [64][176]  (wA+wB | wC-wB)
#define OFF_AB1 11264    // [64]
#define OFF_W2T 11328    // [64][32]   act_w2 transposed -> w2t[o*32+p]
#define OFF_AB2 13376    // [32]
#define OFF_W3  13408    // [32]
#define OFF_AB3 13440    // [1] (padded 16)
#define OFF_M1  13456    // [128][208]
#define OFF_MB1 40080    // [128]
#define OFF_M2T 40208    // [128][64]  mlp_w2 transposed -> m2t[o*64+p]
#define OFF_MB2 48400    // [64]
#define OFF_M3T 48464    // [64][32]   mlp_w3 transposed -> m3t[o*32+p]
#define OFF_MB3 50512    // [32]
#define OFF_M4  50544    // [32]
#define OFF_MB4 50576    // [1]
#define PREP_N  50562

__device__ __forceinline__ void load8(const float4* __restrict__ e, int idx, float* d){
  float4 a = e[idx*2];
  float4 b = e[idx*2+1];
  d[0]=a.x; d[1]=a.y; d[2]=a.z; d[3]=a.w;
  d[4]=b.x; d[5]=b.y; d[6]=b.z; d[7]=b.w;
}

__device__ __forceinline__ void gather_item_feat(const float4* __restrict__ item_emb,
                                                 const float4* __restrict__ kind_emb,
                                                 int item_idx,
                                                 const int* __restrict__ kidx,
                                                 float* f){
  load8(item_emb, item_idx, f);
  #pragma unroll
  for(int k=0;k<KIND_LEN;k++){
    int ki = kidx[k];
    float t[8]; load8(kind_emb, ki, t);
    #pragma unroll
    for(int j=0;j<8;j++) f[8+8*k+j] = ki ? t[j] : 0.0f;
  }
}

typedef const float* fp;

// ---- prep: combine/transpose all weights (fp32) into ws ----
__global__ void din_prep(fp aw1, fp ab1, fp aw2, fp ab2, fp aw3, fp ab3,
                         fp m1,  fp mb1, fp m2,  fp mb2, fp m3,  fp mb3,
                         fp m4,  fp mb4, float* __restrict__ ws){
  int i = blockIdx.x*blockDim.x + threadIdx.x;
  int j = i;
  if(j < 11264){
    int o = j/176, d = j%176;
    float v;
    if(d < 88) v = aw1[o*264 + d] + aw1[o*264 + 88 + d];
    else { int dd = d-88; v = aw1[o*264 + 176 + dd] - aw1[o*264 + 88 + dd]; }
    ws[OFF_WC1 + j] = v; return;
  } j -= 11264;
  if(j < 64){ ws[OFF_AB1 + j] = ab1[j]; return; } j -= 64;
  if(j < 2048){ int o=j/32, p=j%32; ws[OFF_W2T + j] = aw2[p*64 + o]; return; } j -= 2048;
  if(j < 32){ ws[OFF_AB2 + j] = ab2[j]; return; } j -= 32;
  if(j < 32){ ws[OFF_W3  + j] = aw3[j]; return; } j -= 32;
  if(j < 1){ ws[OFF_AB3] = ab3[0]; return; } j -= 1;
  if(j < 26624){ ws[OFF_M1 + j] = m1[j]; return; } j -= 26624;
  if(j < 128){ ws[OFF_MB1 + j] = mb1[j]; return; } j -= 128;
  if(j < 8192){ int o=j/64, p=j%64; ws[OFF_M2T + j] = m2[p*128 + o]; return; } j -= 8192;
  if(j < 64){ ws[OFF_MB2 + j] = mb2[j]; return; } j -= 64;
  if(j < 2048){ int o=j/32, p=j%32; ws[OFF_M3T + j] = m3[p*64 + o]; return; } j -= 2048;
  if(j < 32){ ws[OFF_MB3 + j] = mb3[j]; return; } j -= 32;
  if(j < 32){ ws[OFF_M4  + j] = m4[j];  return; } j -= 32;
  if(j < 1){ ws[OFF_MB4] = mb4[0]; return; }
}

// Block = 128 threads (2 waves) sharing the same 64 samples (lane = sample).
// o-dimensions split across the 2 waves; weights wave-uniform (s_load path);
// cross-wave partials combine via LDS.
// NOTE: __launch_bounds__(128,1): round 4's (128,2) made the backend cap
// VGPRs at 128 -> ~1 KB/thread scratch spill (WRITE_SIZE 135 MB). With cap
// 512 the natural ~200-VGPR allocation still allows 2 waves/SIMD (<=256).
__global__ void __launch_bounds__(128, 1)
din_main(const int* __restrict__ userid, const int* __restrict__ itemid,
         const int* __restrict__ age,    const int* __restrict__ gen,
         const int* __restrict__ occ,    const int* __restrict__ item_kind,
         const int* __restrict__ his_id, const int* __restrict__ his_kind,
         const float4* __restrict__ user_emb, const float4* __restrict__ item_emb,
         const float4* __restrict__ age_emb,  const float4* __restrict__ gen_emb,
         const float4* __restrict__ occ_emb,  const float4* __restrict__ kind_emb,
         const float* __restrict__ ws, float* __restrict__ out){
  const int lane = threadIdx.x & 63;
  const int wave = __builtin_amdgcn_readfirstlane((int)(threadIdx.x >> 6));
  const int b = blockIdx.x*64 + lane;

  __shared__ float ls[8192];   // 32 KB

  // ---- phase A: t2[own 32 o's] = dot(wC-wB, i2) -> LDS ----
  {
    float i2r[88];
    gather_item_feat(item_emb, kind_emb, itemid[b], item_kind + b*KIND_LEN, i2r);
    #pragma unroll 2
    for(int o=0;o<32;o++){
      const float* __restrict__ w = ws + OFF_WC1 + (wave*32+o)*176 + 88;
      float a0=0.f,a1=0.f,a2=0.f,a3=0.f;
      #pragma unroll
      for(int d=0;d<88;d+=4){ a0+=w[d]*i2r[d]; a1+=w[d+1]*i2r[d+1]; a2+=w[d+2]*i2r[d+2]; a3+=w[d+3]*i2r[d+3]; }
      ls[4096 + wave*2048 + o*64 + lane] = (a0+a1)+(a2+a3);
    }
  }

  float pool_own[44];
  #pragma unroll
  for(int d=0;d<44;d++) pool_own[d]=0.f;

  // ---- history positions ----
  #pragma unroll 1
  for(int s=0;s<HIS_LEN;s++){
    float i1[88];
    gather_item_feat(item_emb, kind_emb, his_id[b*HIS_LEN+s], his_kind + (b*HIS_LEN+s)*KIND_LEN, i1);

    float h2p[32];
    #pragma unroll
    for(int p=0;p<32;p++) h2p[p] = (wave==0) ? ws[OFF_AB2+p] : 0.f;

    #pragma unroll 2
    for(int o=0;o<32;o++){
      const float* __restrict__ w = ws + OFF_WC1 + (wave*32+o)*176;
      float a0=0.f,a1=0.f,a2=0.f,a3=0.f;
      #pragma unroll
      for(int d=0;d<88;d+=4){ a0+=w[d]*i1[d]; a1+=w[d+1]*i1[d+1]; a2+=w[d+2]*i1[d+2]; a3+=w[d+3]*i1[d+3]; }
      float h = (a0+a1)+(a2+a3) + ls[4096 + wave*2048 + o*64 + lane] + ws[OFF_AB1 + wave*32 + o];
      h = fmaxf(h, 0.f);
      const float* __restrict__ w2 = ws + OFF_W2T + (wave*32+o)*32;
      #pragma unroll
      for(int p=0;p<32;p++) h2p[p] += w2[p]*h;
    }
    // exchange h2 partials
    #pragma unroll
    for(int p=0;p<32;p++) ls[wave*2048 + p*64 + lane] = h2p[p];
    __syncthreads();
    float sc = ws[OFF_AB3];
    {
      const int ow = (1-wave)*2048;
      #pragma unroll
      for(int p=0;p<32;p++){
        float hf = h2p[p] + ls[ow + p*64 + lane];
        sc += ws[OFF_W3+p]*fmaxf(hf,0.f);
      }
    }
    __syncthreads();   // reads done before next-iter overwrite / pool overwrite
    if(wave==0){
      #pragma unroll
      for(int d=0;d<44;d++){ float v=i1[d];    pool_own[d] += sc*v*v; }
    } else {
      #pragma unroll
      for(int d=0;d<44;d++){ float v=i1[44+d]; pool_own[d] += sc*v*v; }
    }
  }

  // ---- publish pool (full 88) to LDS ----
  if(wave==0){
    #pragma unroll
    for(int d=0;d<44;d++) ls[d*64+lane] = pool_own[d];
  } else {
    #pragma unroll
    for(int d=0;d<44;d++) ls[(44+d)*64+lane] = pool_own[d];
  }
  __syncthreads();

  // ---- main MLP layer 1+2 (own 64 o's of 128), o in blocks of 16, K chunked 104+104 ----
  float h2m[64];
  #pragma unroll
  for(int p=0;p<64;p++) h2m[p] = (wave==0)? ws[OFF_MB2+p] : 0.f;

  // hoisted static rows (user/item/age/gen/occ) -- loaded ONCE, not per og
  float s40[40];
  load8(user_emb, userid[b], s40+0);
  load8(item_emb, itemid[b], s40+8);
  load8(age_emb,  age[b],  s40+16);
  load8(gen_emb,  gen[b],  s40+24);
  load8(occ_emb,  occ[b],  s40+32);

  const int itk = b*KIND_LEN;
  #pragma unroll 1
  for(int og=0; og<4; og++){
    const int obase = wave*64 + og*16;
    float pa[16];
    #pragma unroll
    for(int i=0;i<16;i++) pa[i] = ws[OFF_MB1 + obase + i];
    { // chunk 0: feat[0:104] = s40, kind rows 0..7 (kind_emb is 640 B -> L1 hits)
      float c[104];
      #pragma unroll
      for(int j=0;j<40;j++) c[j] = s40[j];
      #pragma unroll
      for(int k=0;k<8;k++){
        int ki = item_kind[itk+k];
        float t[8]; load8(kind_emb, ki, t);
        #pragma unroll
        for(int j=0;j<8;j++) c[40+8*k+j] = ki? t[j]:0.f;
      }
      #pragma unroll
      for(int i=0;i<16;i++){
        const float* __restrict__ w = ws + OFF_M1 + (obase+i)*208;
        float a0=0.f,a1=0.f,a2=0.f,a3=0.f;
        #pragma unroll
        for(int d=0;d<104;d+=4){ a0+=w[d]*c[d]; a1+=w[d+1]*c[d+1]; a2+=w[d+2]*c[d+2]; a3+=w[d+3]*c[d+3]; }
        pa[i] += (a0+a1)+(a2+a3);
      }
    }
    { // chunk 1: feat[104:208] = kind rows 8,9 + pool[0:88] (from LDS)
      float c[104];
      #pragma unroll
      for(int k=8;k<10;k++){
        int ki = item_kind[itk+k];
        float t[8]; load8(kind_emb, ki, t);
        #pragma unroll
        for(int j=0;j<8;j++) c[(k-8)*8+j] = ki? t[j]:0.f;
      }
      #pragma unroll
      for(int d=0;d<88;d++) c[16+d] = ls[d*64+lane];
      #pragma unroll
      for(int i=0;i<16;i++){
        const float* __restrict__ w = ws + OFF_M1 + (obase+i)*208 + 104;
        float a0=0.f,a1=0.f,a2=0.f,a3=0.f;
        #pragma unroll
        for(int d=0;d<104;d+=4){ a0+=w[d]*c[d]; a1+=w[d+1]*c[d+1]; a2+=w[d+2]*c[d+2]; a3+=w[d+3]*c[d+3]; }
        pa[i] += (a0+a1)+(a2+a3);
      }
    }
    #pragma unroll
    for(int i=0;i<16;i++){
      float h = fmaxf(pa[i], 0.f);
      const float* __restrict__ w2 = ws + OFF_M2T + (obase+i)*64;
      #pragma unroll
      for(int p=0;p<64;p++) h2m[p] += w2[p]*h;
    }
  }
  __syncthreads();   // all pool reads done before overwriting ls[0..4095]

  // ---- h2m exchange: each wave ends with its fully-reduced 32-neuron half ----
  if(wave==0){
    #pragma unroll
    for(int p=32;p<64;p++) ls[2048 + (p-32)*64 + lane] = h2m[p];
  } else {
    #pragma unroll
    for(int p=0;p<32;p++) ls[p*64 + lane] = h2m[p];
  }
  __syncthreads();

  float h3p[32];
  #pragma unroll
  for(int p=0;p<32;p++) h3p[p] = (wave==0)? ws[OFF_MB3+p] : 0.f;

  if(wave==0){
    #pragma unroll
    for(int o2=0;o2<32;o2++){
      float v = fmaxf(h2m[o2] + ls[o2*64+lane], 0.f);
      const float* __restrict__ w3 = ws + OFF_M3T + o2*32;
      #pragma unroll
      for(int p=0;p<32;p++) h3p[p] += w3[p]*v;
    }
  } else {
    #pragma unroll
    for(int o2=0;o2<32;o2++){
      float v = fmaxf(h2m[32+o2] + ls[2048 + o2*64+lane], 0.f);
      const float* __restrict__ w3 = ws + OFF_M3T + (32+o2)*32;
      #pragma unroll
      for(int p=0;p<32;p++) h3p[p] += w3[p]*v;
    }
  }
  __syncthreads();
  if(wave==1){
    #pragma unroll
    for(int p=0;p<32;p++) ls[p*64+lane] = h3p[p];
  }
  __syncthreads();
  if(wave==0){
    float x = ws[OFF_MB4];
    #pragma unroll
    for(int p=0;p<32;p++) x += ws[OFF_M4+p]*fmaxf(h3p[p] + ls[p*64+lane], 0.f);
    out[b] = 1.0f/(1.0f + __expf(-x));
  }
}

extern "C" void kernel_launch(void* const* d_in, const int* in_sizes, int n_in,
                              void* d_out, int out_size, void* d_ws, size_t ws_size,
                              hipStream_t stream){
  const int* userid    = (const int*)d_in[0];
  const int* itemid    = (const int*)d_in[1];
  const int* age       = (const int*)d_in[2];
  const int* gen       = (const int*)d_in[3];
  const int* occ       = (const int*)d_in[4];
  const int* item_kind = (const int*)d_in[5];
  const int* his_id    = (const int*)d_in[6];
  const int* his_kind  = (const int*)d_in[7];
  const float4* user_emb = (const float4*)d_in[8];
  const float4* item_emb = (const float4*)d_in[9];
  const float4* age_emb  = (const float4*)d_in[10];
  const float4* gen_emb  = (const float4*)d_in[11];
  const float4* occ_emb  = (const float4*)d_in[12];
  const float4* kind_emb = (const float4*)d_in[13];
  float* ws = (float*)d_ws;

  din_prep<<<(PREP_N+255)/256, 256, 0, stream>>>(
      (fp)d_in[14], (fp)d_in[15], (fp)d_in[16], (fp)d_in[17], (fp)d_in[18], (fp)d_in[19],
      (fp)d_in[20], (fp)d_in[21], (fp)d_in[22], (fp)d_in[23], (fp)d_in[24], (fp)d_in[25],
      (fp)d_in[26], (fp)d_in[27], ws);

  din_main<<<BATCH/64, 128, 0, stream>>>(
      userid, itemid, age, gen, occ, item_kind, his_id, his_kind,
      user_emb, item_emb, age_emb, gen_emb, occ_emb, kind_emb,
      ws, (float*)d_out);
}

// Round 6
// 962.062 us; speedup vs baseline: 1.5023x; 1.5023x over previous
//
#include <hip/hip_runtime.h>
#include <cstdint>
#include <math.h>

#define BATCH    65536
#define HIS_LEN  5
#define KIND_LEN 10

// ---- ws layout (fp32 element offsets) ----
#define OFF_WC1 0        // [64][176]  (wA+wB | wC-wB)
#define OFF_AB1 11264    // [64]
#define OFF_W2T 11328    // [64][32]
#define OFF_AB2 13376    // [32]
#define OFF_W3  13408    // [32]
#define OFF_AB3 13440    // [1]
#define OFF_M1  13456    // [128][208]
#define OFF_MB1 40080    // [128]
#define OFF_M2T 40208    // [128][64]
#define OFF_MB2 48400    // [64]
#define OFF_M3T 48464    // [64][32]
#define OFF_MB3 50512    // [32]
#define OFF_M4  50544    // [32]
#define OFF_MB4 50576    // [1]
#define PREP_N  50562

// LDS float offsets (total 9092 floats = 36.4 KB -> 4 blocks/CU)
#define LPF 2816   // persistent act: AB1(64) W2T(2048) AB2(32) W3(32) AB3(1) = ws[11264..13441)
#define LTT 4996   // t2[o][lane] 64*64 fp32

__device__ __forceinline__ void load8(const float4* __restrict__ e, int idx, float* d){
  float4 a = e[idx*2];
  float4 b = e[idx*2+1];
  d[0]=a.x; d[1]=a.y; d[2]=a.z; d[3]=a.w;
  d[4]=b.x; d[5]=b.y; d[6]=b.z; d[7]=b.w;
}

__device__ __forceinline__ void gather_item_feat(const float4* __restrict__ item_emb,
                                                 const float4* __restrict__ kind_emb,
                                                 int item_idx,
                                                 const int* __restrict__ kidx,
                                                 float* f){
  load8(item_emb, item_idx, f);
  #pragma unroll
  for(int k=0;k<KIND_LEN;k++){
    int ki = kidx[k];
    float t[8]; load8(kind_emb, ki, t);
    #pragma unroll
    for(int j=0;j<8;j++) f[8+8*k+j] = ki ? t[j] : 0.0f;
  }
}

typedef const float* fp;

// ---- prep: combine/transpose all weights (fp32) into ws (unchanged) ----
__global__ void din_prep(fp aw1, fp ab1, fp aw2, fp ab2, fp aw3, fp ab3,
                         fp m1,  fp mb1, fp m2,  fp mb2, fp m3,  fp mb3,
                         fp m4,  fp mb4, float* __restrict__ ws){
  int i = blockIdx.x*blockDim.x + threadIdx.x;
  int j = i;
  if(j < 11264){
    int o = j/176, d = j%176;
    float v;
    if(d < 88) v = aw1[o*264 + d] + aw1[o*264 + 88 + d];
    else { int dd = d-88; v = aw1[o*264 + 176 + dd] - aw1[o*264 + 88 + dd]; }
    ws[OFF_WC1 + j] = v; return;
  } j -= 11264;
  if(j < 64){ ws[OFF_AB1 + j] = ab1[j]; return; } j -= 64;
  if(j < 2048){ int o=j/32, p=j%32; ws[OFF_W2T + j] = aw2[p*64 + o]; return; } j -= 2048;
  if(j < 32){ ws[OFF_AB2 + j] = ab2[j]; return; } j -= 32;
  if(j < 32){ ws[OFF_W3  + j] = aw3[j]; return; } j -= 32;
  if(j < 1){ ws[OFF_AB3] = ab3[0]; return; } j -= 1;
  if(j < 26624){ ws[OFF_M1 + j] = m1[j]; return; } j -= 26624;
  if(j < 128){ ws[OFF_MB1 + j] = mb1[j]; return; } j -= 128;
  if(j < 8192){ int o=j/64, p=j%64; ws[OFF_M2T + j] = m2[p*128 + o]; return; } j -= 8192;
  if(j < 64){ ws[OFF_MB2 + j] = mb2[j]; return; } j -= 64;
  if(j < 2048){ int o=j/32, p=j%32; ws[OFF_M3T + j] = m3[p*64 + o]; return; } j -= 2048;
  if(j < 32){ ws[OFF_MB3 + j] = mb3[j]; return; } j -= 32;
  if(j < 32){ ws[OFF_M4  + j] = m4[j];  return; } j -= 32;
  if(j < 1){ ws[OFF_MB4] = mb4[0]; return; }
}

// Round-3 skeleton (single wave per 64 samples, lane=sample) with weight rows
// streamed from LDS (ds_read_b128 broadcast) instead of s_load. Chunked
// staging keeps LDS at 36.4 KB -> 4 blocks/CU.
__global__ void __launch_bounds__(64, 1)
din_main(const int* __restrict__ userid, const int* __restrict__ itemid,
         const int* __restrict__ age,    const int* __restrict__ gen,
         const int* __restrict__ occ,    const int* __restrict__ item_kind,
         const int* __restrict__ his_id, const int* __restrict__ his_kind,
         const float4* __restrict__ user_emb, const float4* __restrict__ item_emb,
         const float4* __restrict__ age_emb,  const float4* __restrict__ gen_emb,
         const float4* __restrict__ occ_emb,  const float4* __restrict__ kind_emb,
         const float* __restrict__ ws, float* __restrict__ out){
  const int lane = threadIdx.x;
  const int b = blockIdx.x*64 + lane;

  __shared__ __align__(16) float ls[9092];
  float4* ls4 = (float4*)ls;
  const float4* ws4 = (const float4*)ws;

  // ---- stage persistent act small-weights: ws[11264..13441) -> ls[LPF..] ----
  {
    const float4* srcP = ws4 + 2816;          // 11264/4
    #pragma unroll
    for(int k=0;k<8;k++) ls4[704 + k*64 + lane] = srcP[k*64 + lane];
    if(lane<32) ls4[704 + 512 + lane] = srcP[512 + lane];
    if(lane==0) ls[LPF + 2176] = ws[11264 + 2176];
  }

  // ---- current-item feature i2 ----
  float i2[88];
  gather_item_feat(item_emb, kind_emb, itemid[b], item_kind + b*KIND_LEN, i2);

  // ---- phase A: t2[o] = dot(wC-wB, i2) -> LDS, rows staged 32 at a time ----
  for(int c=0;c<2;c++){
    __syncthreads();
    #pragma unroll
    for(int k=0;k<11;k++){
      int j = k*64 + lane;               // 704 float4 = 32 rows x 22 f4
      int r = j/22, d4 = j - r*22;       // magic-mul div
      ls4[j] = ws4[(c*32 + r)*44 + 22 + d4];
    }
    __syncthreads();
    #pragma unroll 2
    for(int o=0;o<32;o++){
      const float4* wr = ls4 + o*22;
      float a0=0.f,a1=0.f,a2=0.f,a3=0.f;
      #pragma unroll
      for(int d=0;d<22;d++){
        float4 w4 = wr[d];
        a0 += w4.x*i2[4*d]; a1 += w4.y*i2[4*d+1]; a2 += w4.z*i2[4*d+2]; a3 += w4.w*i2[4*d+3];
      }
      ls[LTT + (c*32+o)*64 + lane] = (a0+a1)+(a2+a3);
    }
  }

  float pool[88];
  #pragma unroll
  for(int d=0;d<88;d++) pool[d]=0.f;

  // ---- history positions ----
  #pragma unroll 1
  for(int s=0;s<HIS_LEN;s++){
    float i1[88];
    gather_item_feat(item_emb, kind_emb, his_id[b*HIS_LEN+s], his_kind + (b*HIS_LEN+s)*KIND_LEN, i1);

    float h2[32];
    #pragma unroll
    for(int p=0;p<32;p++) h2[p] = ls[LPF + 2112 + p];   // AB2

    #pragma unroll 1
    for(int c=0;c<2;c++){
      __syncthreads();
      #pragma unroll
      for(int k=0;k<11;k++){
        int j = k*64 + lane;
        int r = j/22, d4 = j - r*22;
        ls4[j] = ws4[(c*32 + r)*44 + d4];   // first halves (wA+wB)
      }
      __syncthreads();
      #pragma unroll 2
      for(int o=0;o<32;o++){
        const float4* wr = ls4 + o*22;
        float a0=0.f,a1=0.f,a2=0.f,a3=0.f;
        #pragma unroll
        for(int d=0;d<22;d++){
          float4 w4 = wr[d];
          a0 += w4.x*i1[4*d]; a1 += w4.y*i1[4*d+1]; a2 += w4.z*i1[4*d+2]; a3 += w4.w*i1[4*d+3];
        }
        float h = (a0+a1)+(a2+a3) + ls[LTT + (c*32+o)*64 + lane] + ls[LPF + c*32 + o];
        h = fmaxf(h, 0.f);
        const float* w2 = ls + LPF + 64 + (c*32+o)*32;  // W2T row
        #pragma unroll
        for(int p=0;p<32;p++) h2[p] += w2[p]*h;
      }
    }
    float sc = ls[LPF + 2176];   // AB3
    #pragma unroll
    for(int p=0;p<32;p++) sc += ls[LPF + 2144 + p]*fmaxf(h2[p],0.f);  // W3
    #pragma unroll
    for(int d=0;d<88;d++){ float t = sc*i1[d]; pool[d] += t*i1[d]; }
  }

  // ---- main MLP ----
  float sA[40];
  load8(user_emb, userid[b], sA+0);
  #pragma unroll
  for(int j=0;j<8;j++) sA[8+j] = i2[j];
  load8(age_emb, age[b], sA+16);
  load8(gen_emb, gen[b], sA+24);
  load8(occ_emb, occ[b], sA+32);

  float h2m[64];
  #pragma unroll
  for(int p=0;p<64;p++) h2m[p] = ws[OFF_MB2 + p];   // uniform s_load, once

  #pragma unroll 1
  for(int c=0;c<4;c++){
    __syncthreads();
    #pragma unroll
    for(int k=0;k<26;k++) ls4[k*64+lane] = ws4[3364 + c*1664 + k*64 + lane];        // M1 rows
    #pragma unroll
    for(int k=0;k<8;k++)  ls4[1664 + k*64+lane] = ws4[10052 + c*512 + k*64 + lane]; // M2T rows
    if(lane<32) ls[8704+lane] = ws[OFF_MB1 + c*32 + lane];                           // MB1
    __syncthreads();
    #pragma unroll 2
    for(int i=0;i<32;i++){
      const float4* wr = ls4 + i*52;
      float a0=0.f,a1=0.f,a2=0.f,a3=0.f;
      #pragma unroll
      for(int j=0;j<10;j++){ float4 w4=wr[j];
        a0+=w4.x*sA[4*j]; a1+=w4.y*sA[4*j+1]; a2+=w4.z*sA[4*j+2]; a3+=w4.w*sA[4*j+3]; }
      #pragma unroll
      for(int j=0;j<20;j++){ float4 w4=wr[10+j];
        a0+=w4.x*i2[8+4*j]; a1+=w4.y*i2[9+4*j]; a2+=w4.z*i2[10+4*j]; a3+=w4.w*i2[11+4*j]; }
      #pragma unroll
      for(int j=0;j<22;j++){ float4 w4=wr[30+j];
        a0+=w4.x*pool[4*j]; a1+=w4.y*pool[4*j+1]; a2+=w4.z*pool[4*j+2]; a3+=w4.w*pool[4*j+3]; }
      float h = fmaxf((a0+a1)+(a2+a3) + ls[8704+i], 0.f);
      const float* w2 = ls + 6656 + i*64;
      #pragma unroll
      for(int p=0;p<64;p++) h2m[p] += w2[p]*h;
    }
  }

  // ---- tail: M3T + MB3/M4/MB4 staged, layers 3+4 ----
  __syncthreads();
  #pragma unroll
  for(int k=0;k<8;k++) ls4[k*64+lane] = ws4[12116 + k*64 + lane];   // M3T 2048 floats
  for(int j=lane; j<65; j+=64) ls[2048+j] = ws[OFF_MB3 + j];        // MB3,M4,MB4
  __syncthreads();

  float h3[32];
  #pragma unroll
  for(int p=0;p<32;p++) h3[p] = ls[2048+p];
  #pragma unroll 2
  for(int o=0;o<64;o++){
    float v = fmaxf(h2m[o],0.f);
    const float* w3 = ls + o*32;
    #pragma unroll
    for(int p=0;p<32;p++) h3[p] += w3[p]*v;
  }
  float x = ls[2112];
  #pragma unroll
  for(int p=0;p<32;p++) x += ls[2080+p]*fmaxf(h3[p],0.f);

  out[b] = 1.0f/(1.0f + __expf(-x));
}

extern "C" void kernel_launch(void* const* d_in, const int* in_sizes, int n_in,
                              void* d_out, int out_size, void* d_ws, size_t ws_size,
                              hipStream_t stream){
  const int* userid    = (const int*)d_in[0];
  const int* itemid    = (const int*)d_in[1];
  const int* age       = (const int*)d_in[2];
  const int* gen       = (const int*)d_in[3];
  const int* occ       = (const int*)d_in[4];
  const int* item_kind = (const int*)d_in[5];
  const int* his_id    = (const int*)d_in[6];
  const int* his_kind  = (const int*)d_in[7];
  const float4* user_emb = (const float4*)d_in[8];
  const float4* item_emb = (const float4*)d_in[9];
  const float4* age_emb  = (const float4*)d_in[10];
  const float4* gen_emb  = (const float4*)d_in[11];
  const float4* occ_emb  = (const float4*)d_in[12];
  const float4* kind_emb = (const float4*)d_in[13];
  float* ws = (float*)d_ws;

  din_prep<<<(PREP_N+255)/256, 256, 0, stream>>>(
      (fp)d_in[14], (fp)d_in[15], (fp)d_in[16], (fp)d_in[17], (fp)d_in[18], (fp)d_in[19],
      (fp)d_in[20], (fp)d_in[21], (fp)d_in[22], (fp)d_in[23], (fp)d_in[24], (fp)d_in[25],
      (fp)d_in[26], (fp)d_in[27], ws);

  din_main<<<BATCH/64, 64, 0, stream>>>(
      userid, itemid, age, gen, occ, item_kind, his_id, his_kind,
      user_emb, item_emb, age_emb, gen_emb, occ_emb, kind_emb,
      ws, (float*)d_out);
}

// Round 8
// 487.249 us; speedup vs baseline: 2.9662x; 1.9745x over previous
//
#include <hip/hip_runtime.h>
#include <cstdint>
#include <math.h>

#define BATCH    65536
#define HIS_LEN  5
#define KIND_LEN 10

// ---- ws layout (fp32 element offsets); WC1 and M1 are stored LANE-SLICED ----
#define OFF_WC1 0        // [64][176] sliced: [q0(22)|q1|q2|q3 | second-88 same]
#define OFF_AB1 11264    // [64]
#define OFF_W2T 11328    // [64][32]
#define OFF_AB2 13376    // [32]
#define OFF_W3  13408    // [32]
#define OFF_AB3 13440    // [1]
#define OFF_M1  13456    // [128][208] sliced: [q slice: ex8|i2part22|pool22]x4
#define OFF_MB1 40080    // [128]
#define OFF_M2T 40208    // [128][64]
#define OFF_MB2 48400    // [64]
#define OFF_M3T 48464    // [64][32]
#define OFF_MB3 50512    // [32]
#define OFF_M4  50544    // [32]
#define OFF_MB4 50576    // [1]
#define PREP_N  50562

// LDS float offsets: STG[0,4368) | P[4368,6674+2) | T(bf16 t2) at 6676 (2048 f-equiv)
#define PF   4368
#define LDSF 8724

typedef const float* fp;

// lane q owns feature elements idx = 8r + 2q + e  (r<11, e<2)  of each 88-vec.
// prep emits weight rows pre-sliced to match.
__global__ void din_prep(fp aw1, fp ab1, fp aw2, fp ab2, fp aw3, fp ab3,
                         fp m1,  fp mb1, fp m2,  fp mb2, fp m3,  fp mb3,
                         fp m4,  fp mb4, float* __restrict__ ws){
  int i = blockIdx.x*blockDim.x + threadIdx.x;
  int j = i;
  if(j < 11264){ // act_w1 combined+sliced
    int o = j/176, t = j%176;
    int h = (t<88)?0:1; int tt = t-88*h;
    int q = tt/22, d = tt-22*q;
    int idx = 8*(d>>1) + 2*q + (d&1);
    float v = (h==0) ? (aw1[o*264+idx] + aw1[o*264+88+idx])
                     : (aw1[o*264+176+idx] - aw1[o*264+88+idx]);
    ws[OFF_WC1 + j] = v; return;
  } j -= 11264;
  if(j < 64){ ws[OFF_AB1 + j] = ab1[j]; return; } j -= 64;
  if(j < 2048){ int o=j/32, p=j%32; ws[OFF_W2T + j] = aw2[p*64 + o]; return; } j -= 2048;
  if(j < 32){ ws[OFF_AB2 + j] = ab2[j]; return; } j -= 32;
  if(j < 32){ ws[OFF_W3  + j] = aw3[j]; return; } j -= 32;
  if(j < 1){ ws[OFF_AB3] = ab3[0]; return; } j -= 1;
  if(j < 26624){ // mlp_w1 sliced: slice_q = [extra8 | i2part22 | poolpart22]
    int o = j/208, r = j%208;
    int q = r/52, t = r-52*q;
    int src;
    if(t<8){ int E = (q==0)?0:(8+8*q); src = E + t; }        // uf/af/gf/qf
    else if(t<30){ int d=t-8; int idx = 8*(d>>1)+2*q+(d&1);
                   src = (idx<8) ? (8+idx) : (32+idx); }      // item+kind
    else { int d=t-30; int idx = 8*(d>>1)+2*q+(d&1); src = 120+idx; } // pool
    ws[OFF_M1 + j] = m1[o*208 + src]; return;
  } j -= 26624;
  if(j < 128){ ws[OFF_MB1 + j] = mb1[j]; return; } j -= 128;
  if(j < 8192){ int o=j/64, p=j%64; ws[OFF_M2T + j] = m2[p*128 + o]; return; } j -= 8192;
  if(j < 64){ ws[OFF_MB2 + j] = mb2[j]; return; } j -= 64;
  if(j < 2048){ int o=j/32, p=j%32; ws[OFF_M3T + j] = m3[p*64 + o]; return; } j -= 2048;
  if(j < 32){ ws[OFF_MB3 + j] = mb3[j]; return; } j -= 32;
  if(j < 32){ ws[OFF_M4  + j] = m4[j];  return; } j -= 32;
  if(j < 1){ ws[OFF_MB4] = mb4[0]; return; }
}

__device__ __forceinline__ float bsum4(float v){
  v += __shfl_xor(v, 1);
  v += __shfl_xor(v, 2);
  return v;
}
__device__ __forceinline__ unsigned short f2bf(float f){
  unsigned int u = __float_as_uint(f);
  return (unsigned short)((u + 0x7fffu + ((u>>16)&1u)) >> 16);
}
__device__ __forceinline__ float bf2f(unsigned short s){
  return __uint_as_float(((unsigned int)s) << 16);
}

// gather this lane's 22-element slice of an 88-feature (item row + 10 masked kind rows)
__device__ __forceinline__ void gather_slice(const float2* __restrict__ itemp,
                                             const float2* __restrict__ kindp,
                                             int item_idx, const int* __restrict__ kidx,
                                             int q, float* f){
  float2 v = itemp[item_idx*4 + q];
  f[0]=v.x; f[1]=v.y;
  #pragma unroll
  for(int r=0;r<KIND_LEN;r++){
    int ki = kidx[r];
    float2 w = kindp[ki*4 + q];
    bool m = (ki!=0);
    f[2+2*r] = m ? w.x : 0.f;
    f[3+2*r] = m ? w.y : 0.f;
  }
}

// block = 256 threads = 4 waves; 64 samples/block; 4 lanes per sample (q=lane&3)
// split the K-dim of every dot 4-way; weights stream via LDS chunk staging.
__global__ void __launch_bounds__(256, 1)
din_main(const int* __restrict__ userid, const int* __restrict__ itemid,
         const int* __restrict__ age,    const int* __restrict__ gen,
         const int* __restrict__ occ,    const int* __restrict__ item_kind,
         const int* __restrict__ his_id, const int* __restrict__ his_kind,
         const float2* __restrict__ user_emb, const float2* __restrict__ item_emb,
         const float2* __restrict__ age_emb,  const float2* __restrict__ gen_emb,
         const float2* __restrict__ occ_emb,  const float2* __restrict__ kind_emb,
         const float* __restrict__ ws, float* __restrict__ out){
  const int tid  = threadIdx.x;
  const int q    = tid & 3;
  const int sl   = (tid & 63) >> 2;
  const int wave = __builtin_amdgcn_readfirstlane(tid >> 6);
  const int b    = blockIdx.x*64 + wave*16 + sl;

  __shared__ __align__(16) float ls[LDSF];
  float4* ls4 = (float4*)ls;
  const float2* ls2 = (const float2*)ls;
  const float4* ws4 = (const float4*)ws;
  unsigned short* tp = (unsigned short*)(ls + 6676);

  // ---- persistent staging: AB1,W2T,AB2,W3,AB3 then MB2 then MB3,M4,MB4 ----
  for(int j=tid; j<2306; j+=256){
    float v;
    if(j<2177)      v = ws[11264 + j];
    else if(j<2241) v = ws[48400 + (j-2177)];
    else            v = ws[50512 + (j-2241)];
    ls[PF + j] = v;
  }

  // ---- i2 slice ----
  float i2[22];
  gather_slice(item_emb, kind_emb, itemid[b], item_kind + b*KIND_LEN, q, i2);

  // ---- phase A: t2 (second-88 dot vs i2) -> bf16 LDS ----
  #pragma unroll 1
  for(int c=0;c<2;c++){
    __syncthreads();
    #pragma unroll
    for(int k=0;k<3;k++){
      int j = k*256 + tid;
      if(j < 704){ int r = j/22, d4 = j - r*22; ls4[j] = ws4[(c*32+r)*44 + 22 + d4]; }
    }
    __syncthreads();
    #pragma unroll 1
    for(int o=0;o<32;o++){
      const float2* wr = ls2 + o*44 + 11*q;
      float a0=0.f,a1=0.f,a2=0.f,a3=0.f;
      #pragma unroll
      for(int d=0;d<11;d++){
        float2 w = wr[d];
        if(d&1){ a2 += w.x*i2[2*d]; a3 += w.y*i2[2*d+1]; }
        else   { a0 += w.x*i2[2*d]; a1 += w.y*i2[2*d+1]; }
      }
      float s = bsum4((a0+a1)+(a2+a3));
      if(q==0) tp[(c*32+o)*64 + wave*16 + sl] = f2bf(s);
    }
  }

  float pool[22];
  #pragma unroll
  for(int d=0;d<22;d++) pool[d]=0.f;

  // ---- history ----
  #pragma unroll 1
  for(int s=0;s<HIS_LEN;s++){
    float i1[22];
    gather_slice(item_emb, kind_emb, his_id[b*HIS_LEN+s],
                 his_kind + (b*HIS_LEN+s)*KIND_LEN, q, i1);

    float h2p[8];
    #pragma unroll
    for(int j=0;j<8;j++) h2p[j]=0.f;

    #pragma unroll 1
    for(int c=0;c<2;c++){
      __syncthreads();
      #pragma unroll
      for(int k=0;k<3;k++){
        int j = k*256 + tid;
        if(j < 704){ int r = j/22, d4 = j - r*22; ls4[j] = ws4[(c*32+r)*44 + d4]; }
      }
      __syncthreads();
      #pragma unroll 1
      for(int o=0;o<32;o++){
        const float2* wr = ls2 + o*44 + 11*q;
        float a0=0.f,a1=0.f,a2=0.f,a3=0.f;
        #pragma unroll
        for(int d=0;d<11;d++){
          float2 w = wr[d];
          if(d&1){ a2 += w.x*i1[2*d]; a3 += w.y*i1[2*d+1]; }
          else   { a0 += w.x*i1[2*d]; a1 += w.y*i1[2*d+1]; }
        }
        float full = bsum4((a0+a1)+(a2+a3));
        int oo = c*32 + o;
        float h = full + bf2f(tp[oo*64 + wave*16 + sl]) + ls[PF + oo];
        h = fmaxf(h, 0.f);
        const float4* w2 = ls4 + 1108 + oo*8 + 2*q;
        float4 wa = w2[0], wb = w2[1];
        h2p[0]+=wa.x*h; h2p[1]+=wa.y*h; h2p[2]+=wa.z*h; h2p[3]+=wa.w*h;
        h2p[4]+=wb.x*h; h2p[5]+=wb.y*h; h2p[6]+=wb.z*h; h2p[7]+=wb.w*h;
      }
    }
    float scp = 0.f;
    #pragma unroll
    for(int j=0;j<8;j++)
      scp += ls[PF+2144+8*q+j] * fmaxf(h2p[j] + ls[PF+2112+8*q+j], 0.f);
    float sc = bsum4(scp) + ls[PF+2176];
    #pragma unroll
    for(int d=0;d<22;d++){ float v = i1[d]; pool[d] += sc*v*v; }
  }

  // ---- MLP extra slice: q selects table (uf/af/gf/qf) ----
  float ex[8];
  {
    const float2* ep = (q==0)? user_emb : (q==1)? age_emb : (q==2)? gen_emb : occ_emb;
    int ei = (q==0)? userid[b] : (q==1)? age[b] : (q==2)? gen[b] : occ[b];
    #pragma unroll
    for(int k=0;k<4;k++){ float2 v = ep[ei*4+k]; ex[2*k]=v.x; ex[2*k+1]=v.y; }
  }

  float h2m[16];
  #pragma unroll
  for(int i=0;i<16;i++) h2m[i] = ls[PF+2177+16*q+i];   // MB2 slice

  // ---- MLP layer 1+2: 8 chunks x 16 rows ----
  #pragma unroll 1
  for(int c=0;c<8;c++){
    __syncthreads();
    #pragma unroll
    for(int k=0;k<4;k++){
      int j = k*256 + tid;
      if(j < 832) ls4[j] = ws4[3364 + c*832 + j];        // M1S rows
    }
    ls4[832 + tid] = ws4[10052 + c*256 + tid];            // M2T rows
    if(tid < 16) ls[4352 + tid] = ws[OFF_MB1 + c*16 + tid];
    __syncthreads();
    #pragma unroll 1
    for(int i=0;i<16;i++){
      const float2* wr = ls2 + i*104 + 26*q;
      float a0=0.f,a1=0.f,a2=0.f,a3=0.f;
      #pragma unroll
      for(int j=0;j<4;j++){ float2 w = wr[j];
        if(j&1){ a2+=w.x*ex[2*j]; a3+=w.y*ex[2*j+1]; } else { a0+=w.x*ex[2*j]; a1+=w.y*ex[2*j+1]; } }
      #pragma unroll
      for(int j=0;j<11;j++){ float2 w = wr[4+j];
        if(j&1){ a2+=w.x*i2[2*j]; a3+=w.y*i2[2*j+1]; } else { a0+=w.x*i2[2*j]; a1+=w.y*i2[2*j+1]; } }
      #pragma unroll
      for(int j=0;j<11;j++){ float2 w = wr[15+j];
        if(j&1){ a2+=w.x*pool[2*j]; a3+=w.y*pool[2*j+1]; } else { a0+=w.x*pool[2*j]; a1+=w.y*pool[2*j+1]; } }
      float h = fmaxf(bsum4((a0+a1)+(a2+a3)) + ls[4352+i], 0.f);
      const float4* w2 = ls4 + 832 + i*16 + 4*q;
      float4 wa=w2[0], wb=w2[1], wc=w2[2], wd=w2[3];
      h2m[0]+=wa.x*h;  h2m[1]+=wa.y*h;  h2m[2]+=wa.z*h;  h2m[3]+=wa.w*h;
      h2m[4]+=wb.x*h;  h2m[5]+=wb.y*h;  h2m[6]+=wb.z*h;  h2m[7]+=wb.w*h;
      h2m[8]+=wc.x*h;  h2m[9]+=wc.y*h;  h2m[10]+=wc.z*h; h2m[11]+=wc.w*h;
      h2m[12]+=wd.x*h; h2m[13]+=wd.y*h; h2m[14]+=wd.z*h; h2m[15]+=wd.w*h;
    }
  }

  // ---- tail: stage M3T, layers 3+4 ----
  __syncthreads();
  #pragma unroll
  for(int k=0;k<2;k++) ls4[k*256 + tid] = ws4[12116 + k*256 + tid];
  __syncthreads();

  float h3p[32];
  #pragma unroll
  for(int j=0;j<32;j++) h3p[j]=0.f;
  #pragma unroll 1
  for(int i=0;i<16;i++){
    float v = fmaxf(h2m[i], 0.f);
    const float4* w3 = ls4 + (16*q + i)*8;
    #pragma unroll
    for(int j=0;j<8;j++){
      float4 w = w3[j];
      h3p[4*j]+=w.x*v; h3p[4*j+1]+=w.y*v; h3p[4*j+2]+=w.z*v; h3p[4*j+3]+=w.w*v;
    }
  }
  #pragma unroll
  for(int j=0;j<32;j++) h3p[j] += __shfl_xor(h3p[j], 1);
  #pragma unroll
  for(int j=0;j<32;j++) h3p[j] += __shfl_xor(h3p[j], 2);

  float x = ls[PF+2305];
  #pragma unroll
  for(int j=0;j<32;j++) x += ls[PF+2273+j] * fmaxf(h3p[j] + ls[PF+2241+j], 0.f);

  if(q==0) out[b] = 1.0f/(1.0f + __expf(-x));
}

extern "C" void kernel_launch(void* const* d_in, const int* in_sizes, int n_in,
                              void* d_out, int out_size, void* d_ws, size_t ws_size,
                              hipStream_t stream){
  const int* userid    = (const int*)d_in[0];
  const int* itemid    = (const int*)d_in[1];
  const int* age       = (const int*)d_in[2];
  const int* gen       = (const int*)d_in[3];
  const int* occ       = (const int*)d_in[4];
  const int* item_kind = (const int*)d_in[5];
  const int* his_id    = (const int*)d_in[6];
  const int* his_kind  = (const int*)d_in[7];
  const float2* user_emb = (const float2*)d_in[8];
  const float2* item_emb = (const float2*)d_in[9];
  const float2* age_emb  = (const float2*)d_in[10];
  const float2* gen_emb  = (const float2*)d_in[11];
  const float2* occ_emb  = (const float2*)d_in[12];
  const float2* kind_emb = (const float2*)d_in[13];
  float* ws = (float*)d_ws;

  din_prep<<<(PREP_N+255)/256, 256, 0, stream>>>(
      (fp)d_in[14], (fp)d_in[15], (fp)d_in[16], (fp)d_in[17], (fp)d_in[18], (fp)d_in[19],
      (fp)d_in[20], (fp)d_in[21], (fp)d_in[22], (fp)d_in[23], (fp)d_in[24], (fp)d_in[25],
      (fp)d_in[26], (fp)d_in[27], ws);

  din_main<<<BATCH/64, 256, 0, stream>>>(
      userid, itemid, age, gen, occ, item_kind, his_id, his_kind,
      user_emb, item_emb, age_emb, gen_emb, occ_emb, kind_emb,
      ws, (float*)d_out);
}

// Round 9
// 417.534 us; speedup vs baseline: 3.4615x; 1.1670x over previous
//
#include <hip/hip_runtime.h>
#include <cstdint>
#include <math.h>

#define BATCH    65536
#define HIS_LEN  5
#define KIND_LEN 10

typedef float v2f __attribute__((ext_vector_type(2)));
__device__ __forceinline__ v2f mk2(float a, float b){ v2f r; r.x=a; r.y=b; return r; }

// ---- ws layout (fp32 element offsets) ----
// WC1: [64 o][2 half][4 q][24] (22 data + 2 pad, 16B-aligned slices)
#define OFF_WC1 0        // 12288
#define OFF_AB1 12288    // 64
#define OFF_W2T 12352    // 2048  [o*32+p]
#define OFF_AB2 14400    // 32
#define OFF_W3  14432    // 32
#define OFF_AB3 14464    // 1
#define OFF_M1  14720    // 26624 [128 o][4 q][52] sliced
#define OFF_MB1 41344    // 128
#define OFF_M2T 41472    // 8192  [o*64+p]
#define OFF_MB2 49664    // 64
#define OFF_M3T 49728    // 2048  [o*32+p]
#define OFF_MB3 51776    // 32
#define OFF_M4  51808    // 32
#define OFF_MB4 51840    // 1
#define PREP_N  51586

// LDS floats: STG[0,3072) | PF[3072,5378) | tp bf16 t2 at 5378 (2048 fl-equiv)
#define PF   3072
#define LDSF 7426

typedef const float* fp;

// lane q owns feature elements idx = 8r + 2q + e (r<11, e<2) of each 88-vec
__global__ void din_prep(fp aw1, fp ab1, fp aw2, fp ab2, fp aw3, fp ab3,
                         fp m1,  fp mb1, fp m2,  fp mb2, fp m3,  fp mb3,
                         fp m4,  fp mb4, float* __restrict__ ws){
  int i = blockIdx.x*blockDim.x + threadIdx.x;
  int j = i;
  if(j < 12288){ // act_w1 combined+sliced+padded
    int o = j/192, t = j%192;
    int h = t/96; int tt = t - 96*h;
    int q = tt/24, d = tt - 24*q;
    float v = 0.f;
    if(d < 22){
      int idx = 8*(d>>1) + 2*q + (d&1);
      v = (h==0) ? (aw1[o*264+idx] + aw1[o*264+88+idx])
                 : (aw1[o*264+176+idx] - aw1[o*264+88+idx]);
    }
    ws[OFF_WC1 + j] = v; return;
  } j -= 12288;
  if(j < 64){ ws[OFF_AB1 + j] = ab1[j]; return; } j -= 64;
  if(j < 2048){ int o=j/32, p=j%32; ws[OFF_W2T + j] = aw2[p*64 + o]; return; } j -= 2048;
  if(j < 32){ ws[OFF_AB2 + j] = ab2[j]; return; } j -= 32;
  if(j < 32){ ws[OFF_W3  + j] = aw3[j]; return; } j -= 32;
  if(j < 1){ ws[OFF_AB3] = ab3[0]; return; } j -= 1;
  if(j < 26624){ // mlp_w1 sliced: [ex8 | i2part22 | poolpart22] per q
    int o = j/208, r = j%208;
    int q = r/52, t = r-52*q;
    int src;
    if(t<8){ int E = (q==0)?0:(8+8*q); src = E + t; }
    else if(t<30){ int d=t-8; int idx = 8*(d>>1)+2*q+(d&1);
                   src = (idx<8) ? (8+idx) : (32+idx); }
    else { int d=t-30; int idx = 8*(d>>1)+2*q+(d&1); src = 120+idx; }
    ws[OFF_M1 + j] = m1[o*208 + src]; return;
  } j -= 26624;
  if(j < 128){ ws[OFF_MB1 + j] = mb1[j]; return; } j -= 128;
  if(j < 8192){ int o=j/64, p=j%64; ws[OFF_M2T + j] = m2[p*128 + o]; return; } j -= 8192;
  if(j < 64){ ws[OFF_MB2 + j] = mb2[j]; return; } j -= 64;
  if(j < 2048){ int o=j/32, p=j%32; ws[OFF_M3T + j] = m3[p*64 + o]; return; } j -= 2048;
  if(j < 32){ ws[OFF_MB3 + j] = mb3[j]; return; } j -= 32;
  if(j < 32){ ws[OFF_M4  + j] = m4[j];  return; } j -= 32;
  if(j < 1){ ws[OFF_MB4] = mb4[0]; return; }
}

__device__ __forceinline__ float bsum4(float v){
  v += __shfl_xor(v, 1);
  v += __shfl_xor(v, 2);
  return v;
}
__device__ __forceinline__ unsigned short f2bf(float f){
  unsigned int u = __float_as_uint(f);
  return (unsigned short)((u + 0x7fffu + ((u>>16)&1u)) >> 16);
}
__device__ __forceinline__ float bf2f(unsigned short s){
  return __uint_as_float(((unsigned int)s) << 16);
}

__device__ __forceinline__ void gather_slice(const float2* __restrict__ itemp,
                                             const float2* __restrict__ kindp,
                                             int item_idx, const int* __restrict__ kidx,
                                             int q, v2f* f){
  float2 v = itemp[item_idx*4 + q];
  f[0] = mk2(v.x, v.y);
  #pragma unroll
  for(int r=0;r<KIND_LEN;r++){
    int ki = kidx[r];
    float2 w = kindp[ki*4 + q];
    bool m = (ki!=0);
    f[1+r] = m ? mk2(w.x, w.y) : mk2(0.f, 0.f);
  }
}

#define PKF(acc, a, b, vv) do{ (acc) = __builtin_elementwise_fma(mk2((a),(b)), (vv), (acc)); }while(0)

// block = 256 threads; 64 samples/block; quad (q=lane&3) K-splits every dot.
__global__ void __launch_bounds__(256, 5)
din_main(const int* __restrict__ userid, const int* __restrict__ itemid,
         const int* __restrict__ age,    const int* __restrict__ gen,
         const int* __restrict__ occ,    const int* __restrict__ item_kind,
         const int* __restrict__ his_id, const int* __restrict__ his_kind,
         const float2* __restrict__ user_emb, const float2* __restrict__ item_emb,
         const float2* __restrict__ age_emb,  const float2* __restrict__ gen_emb,
         const float2* __restrict__ occ_emb,  const float2* __restrict__ kind_emb,
         const float* __restrict__ ws, float* __restrict__ out){
  const int tid  = threadIdx.x;
  const int q    = tid & 3;
  const int sl   = (tid & 63) >> 2;
  const int wave = __builtin_amdgcn_readfirstlane(tid >> 6);
  const int b    = blockIdx.x*64 + wave*16 + sl;

  __shared__ __align__(16) float ls[LDSF];
  float4* ls4 = (float4*)ls;
  const float4* ws4 = (const float4*)ws;
  unsigned short* tp = (unsigned short*)(ls + 5378);

  // ---- persistent staging: AB1,W2T,AB2,W3,AB3 | MB2 | MB3,M4,MB4 ----
  for(int j=tid; j<2306; j+=256){
    float v;
    if(j<2177)      v = ws[12288 + j];
    else if(j<2241) v = ws[49664 + (j-2177)];
    else            v = ws[51776 + (j-2241)];
    ls[PF + j] = v;
  }

  // ---- i2 slice ----
  v2f i2v[11];
  gather_slice(item_emb, kind_emb, itemid[b], item_kind + b*KIND_LEN, q, i2v);

  // ---- phase A: t2 -> bf16 LDS (second-half rows vs i2) ----
  #pragma unroll 1
  for(int c=0;c<2;c++){
    __syncthreads();
    #pragma unroll
    for(int k=0;k<3;k++){
      int j = k*256 + tid;                  // 768 f4 = 32 rows x 24 f4 (half h=1)
      int r = j/24, d4 = j - r*24;
      ls4[j] = ws4[(c*32 + r)*48 + 24 + d4];
    }
    __syncthreads();
    #pragma unroll 1
    for(int o=0;o<32;o++){
      const float4* wr = ls4 + o*24 + 6*q;
      v2f aA = mk2(0.f,0.f), aB = mk2(0.f,0.f);
      #pragma unroll
      for(int k=0;k<5;k++){
        float4 w = wr[k];
        PKF(aA, w.x, w.y, i2v[2*k]);
        PKF(aB, w.z, w.w, i2v[2*k+1]);
      }
      { float4 w = wr[5]; PKF(aA, w.x, w.y, i2v[10]); }
      float s = bsum4((aA.x+aB.x)+(aA.y+aB.y));
      if(q==0) tp[(c*32+o)*64 + wave*16 + sl] = f2bf(s);
    }
  }

  v2f poolv[11];
  #pragma unroll
  for(int d=0;d<11;d++) poolv[d]=mk2(0.f,0.f);

  // ---- history ----
  #pragma unroll 1
  for(int s=0;s<HIS_LEN;s++){
    v2f i1v[11];
    gather_slice(item_emb, kind_emb, his_id[b*HIS_LEN+s],
                 his_kind + (b*HIS_LEN+s)*KIND_LEN, q, i1v);

    v2f h2v[4];
    #pragma unroll
    for(int j=0;j<4;j++) h2v[j]=mk2(0.f,0.f);

    #pragma unroll 1
    for(int c=0;c<2;c++){
      __syncthreads();
      #pragma unroll
      for(int k=0;k<3;k++){
        int j = k*256 + tid;
        int r = j/24, d4 = j - r*24;
        ls4[j] = ws4[(c*32 + r)*48 + d4];   // half h=0 (wA+wB)
      }
      __syncthreads();
      #pragma unroll 1
      for(int o=0;o<32;o++){
        const float4* wr = ls4 + o*24 + 6*q;
        v2f aA = mk2(0.f,0.f), aB = mk2(0.f,0.f);
        #pragma unroll
        for(int k=0;k<5;k++){
          float4 w = wr[k];
          PKF(aA, w.x, w.y, i1v[2*k]);
          PKF(aB, w.z, w.w, i1v[2*k+1]);
        }
        { float4 w = wr[5]; PKF(aA, w.x, w.y, i1v[10]); }
        float full = bsum4((aA.x+aB.x)+(aA.y+aB.y));
        int oo = c*32 + o;
        float h = full + bf2f(tp[oo*64 + wave*16 + sl]) + ls[PF + oo];
        h = fmaxf(h, 0.f);
        v2f hh = mk2(h, h);
        float4 wa = ls4[784 + oo*8 + 2*q];
        float4 wb = ls4[785 + oo*8 + 2*q];
        PKF(h2v[0], wa.x, wa.y, hh);
        PKF(h2v[1], wa.z, wa.w, hh);
        PKF(h2v[2], wb.x, wb.y, hh);
        PKF(h2v[3], wb.z, wb.w, hh);
      }
    }
    float scp = 0.f;
    #pragma unroll
    for(int jj=0;jj<4;jj++){
      float hx = fmaxf(h2v[jj].x + ls[PF+2112+8*q+2*jj],   0.f);
      float hy = fmaxf(h2v[jj].y + ls[PF+2112+8*q+2*jj+1], 0.f);
      scp += ls[PF+2144+8*q+2*jj]*hx + ls[PF+2144+8*q+2*jj+1]*hy;
    }
    float sc = bsum4(scp) + ls[PF+2176];
    v2f scv = mk2(sc, sc);
    #pragma unroll
    for(int d=0;d<11;d++){
      v2f t = i1v[d]*scv;
      poolv[d] = __builtin_elementwise_fma(t, i1v[d], poolv[d]);
    }
  }

  // ---- MLP extra slice (q selects table) ----
  v2f exv[4];
  {
    const float2* ep = (q==0)? user_emb : (q==1)? age_emb : (q==2)? gen_emb : occ_emb;
    int ei = (q==0)? userid[b] : (q==1)? age[b] : (q==2)? gen[b] : occ[b];
    #pragma unroll
    for(int k=0;k<4;k++){ float2 v = ep[ei*4+k]; exv[k]=mk2(v.x,v.y); }
  }

  v2f h2m[8];
  #pragma unroll
  for(int j=0;j<8;j++) h2m[j] = mk2(ls[PF+2177+16*q+2*j], ls[PF+2177+16*q+2*j+1]);

  // ---- MLP layers 1+2: 16 chunks x 8 rows ----
  #pragma unroll 1
  for(int c=0;c<16;c++){
    __syncthreads();
    {
      int j = tid;                 // 544 f4: M1S 416 | M2T 128
      if(j < 416)      ls4[j] = ws4[3680 + c*416 + j];
      else if(j < 544) ls4[j] = ws4[10368 + c*128 + (j-416)];
      j = 256 + tid;
      if(j < 416)      ls4[j] = ws4[3680 + c*416 + j];
      else if(j < 544) ls4[j] = ws4[10368 + c*128 + (j-416)];
      j = 512 + tid;
      if(j < 544)      ls4[j] = ws4[10368 + c*128 + (j-416)];
      if(tid < 8) ls[2900 + tid] = ws[OFF_MB1 + c*8 + tid];
    }
    __syncthreads();
    #pragma unroll 1
    for(int i=0;i<8;i++){
      const float4* wr = ls4 + i*52 + 13*q;
      v2f aA = mk2(0.f,0.f), aB = mk2(0.f,0.f);
      { float4 w = wr[0]; PKF(aA, w.x, w.y, exv[0]); PKF(aB, w.z, w.w, exv[1]); }
      { float4 w = wr[1]; PKF(aA, w.x, w.y, exv[2]); PKF(aB, w.z, w.w, exv[3]); }
      #pragma unroll
      for(int k=0;k<5;k++){
        float4 w = wr[2+k];
        PKF(aA, w.x, w.y, i2v[2*k]);
        PKF(aB, w.z, w.w, i2v[2*k+1]);
      }
      { float4 w = wr[7]; PKF(aA, w.x, w.y, i2v[10]); PKF(aB, w.z, w.w, poolv[0]); }
      #pragma unroll
      for(int k=0;k<5;k++){
        float4 w = wr[8+k];
        PKF(aA, w.x, w.y, poolv[2*k+1]);
        PKF(aB, w.z, w.w, poolv[2*k+2]);
      }
      float h = fmaxf(bsum4((aA.x+aB.x)+(aA.y+aB.y)) + ls[2900+i], 0.f);
      v2f hh = mk2(h, h);
      const float4* w2 = ls4 + 416 + i*16 + 4*q;
      #pragma unroll
      for(int k=0;k<4;k++){
        float4 w = w2[k];
        PKF(h2m[2*k],   w.x, w.y, hh);
        PKF(h2m[2*k+1], w.z, w.w, hh);
      }
    }
  }

  // ---- tail: stage M3T with per-q skew (row 16q+i at f4 q*130+i*8) ----
  __syncthreads();
  #pragma unroll
  for(int k=0;k<2;k++){
    int j = k*256 + tid;
    ls4[(j>>7)*130 + (j&127)] = ws4[12432 + j];
  }
  __syncthreads();

  float h3p[32];
  #pragma unroll
  for(int j=0;j<32;j++) h3p[j]=0.f;
  #pragma unroll
  for(int i=0;i<16;i++){
    float hv = (i&1) ? h2m[i>>1].y : h2m[i>>1].x;
    float v = fmaxf(hv, 0.f);
    const float4* w3 = ls4 + q*130 + i*8;
    #pragma unroll
    for(int j=0;j<8;j++){
      float4 w = w3[j];
      h3p[4*j]+=w.x*v; h3p[4*j+1]+=w.y*v; h3p[4*j+2]+=w.z*v; h3p[4*j+3]+=w.w*v;
    }
  }
  #pragma unroll
  for(int j=0;j<32;j++) h3p[j] += __shfl_xor(h3p[j], 1);
  #pragma unroll
  for(int j=0;j<32;j++) h3p[j] += __shfl_xor(h3p[j], 2);

  float x = ls[PF+2305];
  #pragma unroll
  for(int j=0;j<32;j++) x += ls[PF+2273+j] * fmaxf(h3p[j] + ls[PF+2241+j], 0.f);

  if(q==0) out[b] = 1.0f/(1.0f + __expf(-x));
}

extern "C" void kernel_launch(void* const* d_in, const int* in_sizes, int n_in,
                              void* d_out, int out_size, void* d_ws, size_t ws_size,
                              hipStream_t stream){
  const int* userid    = (const int*)d_in[0];
  const int* itemid    = (const int*)d_in[1];
  const int* age       = (const int*)d_in[2];
  const int* gen       = (const int*)d_in[3];
  const int* occ       = (const int*)d_in[4];
  const int* item_kind = (const int*)d_in[5];
  const int* his_id    = (const int*)d_in[6];
  const int* his_kind  = (const int*)d_in[7];
  const float2* user_emb = (const float2*)d_in[8];
  const float2* item_emb = (const float2*)d_in[9];
  const float2* age_emb  = (const float2*)d_in[10];
  const float2* gen_emb  = (const float2*)d_in[11];
  const float2* occ_emb  = (const float2*)d_in[12];
  const float2* kind_emb = (const float2*)d_in[13];
  float* ws = (float*)d_ws;

  din_prep<<<(PREP_N+255)/256, 256, 0, stream>>>(
      (fp)d_in[14], (fp)d_in[15], (fp)d_in[16], (fp)d_in[17], (fp)d_in[18], (fp)d_in[19],
      (fp)d_in[20], (fp)d_in[21], (fp)d_in[22], (fp)d_in[23], (fp)d_in[24], (fp)d_in[25],
      (fp)d_in[26], (fp)d_in[27], ws);

  din_main<<<BATCH/64, 256, 0, stream>>>(
      userid, itemid, age, gen, occ, item_kind, his_id, his_kind,
      user_emb, item_emb, age_emb, gen_emb, occ_emb, kind_emb,
      ws, (float*)d_out);
}